// Round 1
// baseline (10973.747 us; speedup 1.0000x reference)
//
#include <hip/hip_runtime.h>
#include <stdint.h>

// SPINN thin-stack TreeLSTM, MI355X persistent-group design.
// 32 groups x 8 blocks; group owns 8 batch elems; block owns 16 H-dims
// (80 gate cols), W-slice resident in VGPRs (160 regs/thread, loaded once).
// Cross-block h/c exchange via agent-scope atomics (LLC-coherent across XCDs),
// per-group per-step arrival counters in d_ws.

#define D     512
#define NBAT  256
#define HD    128
#define LD    64
#define KDIM  320   // L + 2H
#define COLS  80    // 5 gates * 16 dims
#define QB    8     // batch per group
#define DIMS  16    // H-dims per block
#define NTHR  320
#define XS_STRIDE 12  // 8 batch + 4 pad (float4-aligned rows, kg-spread banks)

__device__ __forceinline__ float sigf(float x) { return 1.0f / (1.0f + __expf(-x)); }
__device__ __forceinline__ float tanh_(float x) { return 1.0f - 2.0f / (__expf(2.0f * x) + 1.0f); }

__device__ __forceinline__ float gload(const float* p) {
  return __hip_atomic_load(p, __ATOMIC_RELAXED, __HIP_MEMORY_SCOPE_AGENT);
}
__device__ __forceinline__ void gstore(float* p, float v) {
  __hip_atomic_store(p, v, __ATOMIC_RELAXED, __HIP_MEMORY_SCOPE_AGENT);
}

__global__ void zero_cnt_kernel(unsigned* cnt, int n) {
  int i = blockIdx.x * blockDim.x + threadIdx.x;
  if (i < n) cnt[i] = 0u;
}

__global__ __launch_bounds__(NTHR, 1) void spinn_kernel(
    const int* __restrict__ trans, const int* __restrict__ labels,
    const float* __restrict__ emb, const float* __restrict__ W,
    const float* __restrict__ bias, const float* __restrict__ leaf,
    float* __restrict__ out, unsigned* __restrict__ cnt,
    float* __restrict__ h_st, float* __restrict__ c_st)
{
  const int bid = blockIdx.x;
  const int bg  = bid >> 3;   // batch group 0..31  (batch [bg*8, bg*8+8))
  const int ct  = bid & 7;    // col block 0..7     (dims  [ct*16, ct*16+16))
  const int tid = threadIdx.x;

  __shared__ __align__(16) float xs[KDIM * XS_STRIDE];
  __shared__ float gates[QB * COLS];
  __shared__ float bsl[COLS];
  __shared__ unsigned short stk[QB][D];
  __shared__ int pptr[QB];
  __shared__ int lidxA[QB], ridxA[QB], maskA[QB];

  // thread tiling: tid = (cq*2 + bq)*8 + kg
  const int kg = tid & 7;          // interleaved K-split: k == kg (mod 8)
  const int bq = (tid >> 3) & 1;   // batch quad (4 elems)
  const int cq = tid >> 4;         // 0..19: 4 local cols each
  // local col c = g*16 + dl  (g in {i,fl,fr,o,u}); thread cols cq*4..cq*4+3
  const int gcol = (cq >> 2) * HD + ct * DIMS + (cq & 3) * 4;  // global col base

  // --- weight slice into registers: 40 k-values x 4 cols (loaded once) ---
  float4 wr[40];
#pragma unroll
  for (int j = 0; j < 40; ++j) {
    int k = j * 8 + kg;
    wr[j] = *(const float4*)(W + (size_t)k * 640 + gcol);
  }
  if (tid < COLS) {
    int g = tid >> 4, dl = tid & 15;
    bsl[tid] = bias[g * HD + ct * DIMS + dl];
  }
  if (tid < QB) pptr[tid] = 0;
  __syncthreads();

  for (int t = 0; t < D; ++t) {
    // wait for whole group to publish step t-1 (relaxed; data flows via LLC)
    if (t > 0 && tid == 0) {
      int it = 0;
      while (__hip_atomic_load(cnt + (t - 1) * 32 + bg, __ATOMIC_RELAXED,
                               __HIP_MEMORY_SCOPE_AGENT) < (unsigned)QB) {
        __builtin_amdgcn_s_sleep(1);
        if (++it > (1 << 22)) break;  // safety: break hang into wrong-answer
      }
    }
    __syncthreads();

    // --- per-batch idx-stack update (block-local, redundant per group) ---
    if (tid < QB) {
      int b = tid, gb = bg * QB + b;
      int m = trans[t * NBAT + gb];
      int p = pptr[b];
      int li = 0, ri = 0;
      if (m) { ri = stk[b][p - 1]; li = stk[b][p - 2]; }  // right popped first
      int np = p - 2 * m;
      stk[b][np] = (unsigned short)t;  // push current step (always)
      pptr[b] = np + 1;
      lidxA[b] = li; ridxA[b] = ri; maskA[b] = m;
    }
    __syncthreads();

    // --- gather x = [lab(64) | hl(128) | hr(128)] for 8 batch -> xs[k][b] ---
    {
      const int b = tid / 40, seg = tid - b * 40;   // k = seg + 40*i
      const int gb = bg * QB + b;
      const int m = maskA[b], li = lidxA[b], ri = ridxA[b];
      const int row = labels[t * NBAT + gb];
#pragma unroll
      for (int i = 0; i < 8; ++i) {
        int k = seg + 40 * i;
        float v;
        if (k < LD) {
          v = emb[(size_t)row * LD + k];
        } else if (k < LD + HD) {
          int kk = k - LD;
          v = m ? gload(h_st + ((size_t)li * NBAT + gb) * HD + kk) : leaf[kk];
        } else {
          int kk = k - LD - HD;
          v = m ? gload(h_st + ((size_t)ri * NBAT + gb) * HD + kk) : leaf[kk];
        }
        xs[k * XS_STRIDE + b] = v;
      }
    }
    __syncthreads();

    // --- GEMM: gates[8b x 80c] = x^T * Wslice  (W in regs, x from LDS) ---
    float acc[4][4] = {{0.f,0.f,0.f,0.f},{0.f,0.f,0.f,0.f},
                       {0.f,0.f,0.f,0.f},{0.f,0.f,0.f,0.f}};
#pragma unroll
    for (int j = 0; j < 40; ++j) {
      int k = j * 8 + kg;
      float4 xv = *(const float4*)(xs + k * XS_STRIDE + bq * 4);
      float4 wv = wr[j];
      float xx[4] = {xv.x, xv.y, xv.z, xv.w};
      float ww[4] = {wv.x, wv.y, wv.z, wv.w};
#pragma unroll
      for (int ci = 0; ci < 4; ++ci)
#pragma unroll
        for (int bi = 0; bi < 4; ++bi)
          acc[ci][bi] = __builtin_fmaf(ww[ci], xx[bi], acc[ci][bi]);
    }
    // reduce 8-way K-split (kg in low 3 lane bits)
#pragma unroll
    for (int mm = 1; mm < 8; mm <<= 1)
#pragma unroll
      for (int ci = 0; ci < 4; ++ci)
#pragma unroll
        for (int bi = 0; bi < 4; ++bi)
          acc[ci][bi] += __shfl_xor(acc[ci][bi], mm, 64);
    if (kg == 0) {
#pragma unroll
      for (int ci = 0; ci < 4; ++ci)
#pragma unroll
        for (int bi = 0; bi < 4; ++bi)
          gates[(bq * 4 + bi) * COLS + cq * 4 + ci] = acc[ci][bi];
    }
    __syncthreads();

    // --- elementwise TreeLSTM cell for (8 batch x 16 dims) ---
    if (tid < QB * DIMS) {
      const int b = tid >> 4, dl = tid & 15;
      const int gb = bg * QB + b;
      const int d = ct * DIMS + dl;
      float gi  = gates[b * COLS + dl]      + bsl[dl];
      float gfl = gates[b * COLS + 16 + dl] + bsl[16 + dl];
      float gfr = gates[b * COLS + 32 + dl] + bsl[32 + dl];
      float go  = gates[b * COLS + 48 + dl] + bsl[48 + dl];
      float gu  = gates[b * COLS + 64 + dl] + bsl[64 + dl];
      float cl, cr;
      if (maskA[b]) {
        cl = gload(c_st + ((size_t)lidxA[b] * NBAT + gb) * HD + d);
        cr = gload(c_st + ((size_t)ridxA[b] * NBAT + gb) * HD + d);
      } else {
        cl = leaf[d]; cr = leaf[d];
      }
      float cc = sigf(gi) * tanh_(gu) + sigf(gfl) * cl + sigf(gfr) * cr;
      float hh = sigf(go) * tanh_(cc);
      size_t so = ((size_t)t * NBAT + gb) * HD + d;
      gstore(h_st + so, hh);
      gstore(c_st + so, cc);
      if (t == D - 1) {
        out[(size_t)gb * HD + d] = cc;                       // c_st[D-1]
        out[(size_t)NBAT * HD + (size_t)gb * HD + d] = hh;   // h_st[D-1]
      }
    }
    __syncthreads();   // emits s_waitcnt vmcnt(0) per wave -> stores at LLC
    if (tid == 0)
      __hip_atomic_fetch_add(cnt + t * 32 + bg, 1u, __ATOMIC_RELEASE,
                             __HIP_MEMORY_SCOPE_AGENT);
  }
}

extern "C" void kernel_launch(void* const* d_in, const int* in_sizes, int n_in,
                              void* d_out, int out_size, void* d_ws, size_t ws_size,
                              hipStream_t stream) {
  (void)in_sizes; (void)n_in; (void)out_size; (void)ws_size;
  const int*   trans  = (const int*)d_in[0];
  const int*   labels = (const int*)d_in[1];
  const float* emb    = (const float*)d_in[2];
  const float* W      = (const float*)d_in[3];
  const float* bias   = (const float*)d_in[4];
  const float* leaf   = (const float*)d_in[5];
  float* out = (float*)d_out;

  // ws layout: [0,64KB) arrival counters | 128KB: h_st (64MB) | c_st (64MB)
  uint8_t* ws = (uint8_t*)d_ws;
  unsigned* cnt = (unsigned*)ws;
  float* h_st = (float*)(ws + (1 << 17));
  float* c_st = h_st + (size_t)D * NBAT * HD;

  zero_cnt_kernel<<<dim3((D * 32 + 255) / 256), dim3(256), 0, stream>>>(cnt, D * 32);
  spinn_kernel<<<dim3(256), dim3(NTHR), 0, stream>>>(
      trans, labels, emb, W, bias, leaf, out, cnt, h_st, c_st);
}

// Round 2
// 4202.522 us; speedup vs baseline: 2.6112x; 2.6112x over previous
//
#include <hip/hip_runtime.h>
#include <stdint.h>

// SPINN thin-stack TreeLSTM, MI355X persistent-group design, round 2.
// 32 groups x 8 blocks; group owns 8 batch elems; block owns 16 H-dims
// (80 gate cols), W-slice resident in VGPRs/AGPRs (loaded once).
// R2 changes vs R1 (fix LLC same-line sync contention, 49k stall cyc/step):
//  - per-(step,group) sync state padded to its own 64B line (was 16 groups/line)
//  - no atomic RMW: each block release-stores its own flag BYTE; poller
//    reads one u64 and compares 0x0101...01
//  - emb/leaf part of x prefetched BEFORE the wait (only hl/hr need t-1)
//  - next-step stack indices computed concurrently with cell (double-buffered)
//  - LLC h-gather vectorized to u64 chunks

#define D     512
#define NBAT  256
#define HD    128
#define LD    64
#define KDIM  320   // L + 2H
#define COLS  80    // 5 gates * 16 dims
#define QB    8     // batch per group
#define DIMS  16    // H-dims per block
#define NTHR  320
#define XSS   12    // xs row stride (8 batch + 4 pad)
#define FLGS  64    // bytes per (t,group) flag line

__device__ __forceinline__ float sigf(float x) { return 1.0f / (1.0f + __expf(-x)); }
__device__ __forceinline__ float tanh_(float x) { return 1.0f - 2.0f / (__expf(2.0f * x) + 1.0f); }

__device__ __forceinline__ unsigned long long gload64(const float* p) {
  return __hip_atomic_load((const unsigned long long*)p, __ATOMIC_RELAXED,
                           __HIP_MEMORY_SCOPE_AGENT);
}
__device__ __forceinline__ float gload32(const float* p) {
  return __hip_atomic_load(p, __ATOMIC_RELAXED, __HIP_MEMORY_SCOPE_AGENT);
}
__device__ __forceinline__ void gstore32(float* p, float v) {
  __hip_atomic_store(p, v, __ATOMIC_RELAXED, __HIP_MEMORY_SCOPE_AGENT);
}

__global__ void zero_kernel(unsigned* p, int n) {
  int i = blockIdx.x * blockDim.x + threadIdx.x;
  if (i < n) p[i] = 0u;
}

__global__ __launch_bounds__(NTHR, 1) void spinn_kernel(
    const int* __restrict__ trans, const int* __restrict__ labels,
    const float* __restrict__ emb, const float* __restrict__ W,
    const float* __restrict__ bias, const float* __restrict__ leaf,
    float* __restrict__ out, uint8_t* __restrict__ flg,
    float* __restrict__ h_st, float* __restrict__ c_st)
{
  const int bid = blockIdx.x;
  const int bg  = bid >> 3;   // batch group 0..31
  const int ct  = bid & 7;    // col block 0..7
  const int tid = threadIdx.x;

  __shared__ __align__(16) float xs[KDIM * XSS];
  __shared__ float gates[QB * COLS];
  __shared__ float bsl[COLS];
  __shared__ float lsh[HD];
  __shared__ unsigned short stk[QB][D];
  __shared__ int pptr[QB];
  __shared__ int lidxA[2][QB], ridxA[2][QB], maskA[2][QB];

  // thread tiling for GEMM: tid = (cq*2 + bq)*8 + kg
  const int kg = tid & 7;
  const int bq = (tid >> 3) & 1;
  const int cq = tid >> 4;   // 0..19
  const int gcol = (cq >> 2) * HD + ct * DIMS + (cq & 3) * 4;

  // weight slice into registers (once)
  float4 wr[40];
#pragma unroll
  for (int j = 0; j < 40; ++j) {
    int k = j * 8 + kg;
    wr[j] = *(const float4*)(W + (size_t)k * 640 + gcol);
  }
  if (tid < COLS) {
    int g = tid >> 4, dl = tid & 15;
    bsl[tid] = bias[g * HD + ct * DIMS + dl];
  }
  if (tid < HD) lsh[tid] = leaf[tid];
  // stack init + step-0 indices (updater threads 256..263)
  if (tid >= 256 && tid < 256 + QB) {
    int b = tid - 256, gb = bg * QB + b;
    int m = trans[gb];          // generator guarantees m==0 at t=0
    int li = 0, ri = 0, p = 0;
    if (m) { ri = stk[b][p - 1]; li = stk[b][p - 2]; }
    int np = p - 2 * m;
    stk[b][np] = 0;
    pptr[b] = np + 1;
    lidxA[0][b] = li; ridxA[0][b] = ri; maskA[0][b] = m;
  }
  __syncthreads();

  const unsigned long long GOAL = 0x0101010101010101ULL;

  for (int t = 0; t < D; ++t) {
    const int pb = t & 1;

    // --- phase A: poller waits for step t-1; others prefetch emb/leaf ---
    if (tid == 319) {
      if (t > 0) {
        const uint8_t* fp = flg + ((size_t)(t - 1) * 32 + bg) * FLGS;
        int it = 0;
        while (__hip_atomic_load((const unsigned long long*)fp, __ATOMIC_RELAXED,
                                 __HIP_MEMORY_SCOPE_AGENT) != GOAL) {
          __builtin_amdgcn_s_sleep(2);
          if (++it > (1 << 21)) break;  // safety: hang -> wrong answer
        }
      }
    } else {
      // emb: 256 u64 chunks (k < 64), one per thread tid<256
      if (tid < 256) {
        int b = tid >> 5, kk = (tid & 31) * 2;
        int gb = bg * QB + b;
        int row = labels[t * NBAT + gb];
        float2 f = *(const float2*)(emb + (size_t)row * LD + kk);
        xs[kk * XSS + b] = f.x;
        xs[(kk + 1) * XSS + b] = f.y;
      }
      // leaf fill for unmasked elems (k >= 64): 1024 u64 chunks
      for (int c = tid; c < 1024; c += 319) {
        int b = c >> 7;
        if (!maskA[pb][b]) {
          int rem = c & 127, side = rem >> 6, kk = (rem & 63) * 2;
          xs[(LD + side * HD + kk) * XSS + b] = lsh[kk];
          xs[(LD + side * HD + kk + 1) * XSS + b] = lsh[kk + 1];
        }
      }
    }
    __syncthreads();

    // --- phase B: masked hl/hr gather from LLC (u64 chunks) ---
    for (int c = tid; c < 1024; c += NTHR) {
      int b = c >> 7;
      if (maskA[pb][b]) {
        int rem = c & 127, side = rem >> 6, kk = (rem & 63) * 2;
        int gb = bg * QB + b;
        int idx = side ? ridxA[pb][b] : lidxA[pb][b];
        unsigned long long v = gload64(h_st + ((size_t)idx * NBAT + gb) * HD + kk);
        union { unsigned long long u; float f[2]; } cv; cv.u = v;
        xs[(LD + side * HD + kk) * XSS + b] = cv.f[0];
        xs[(LD + side * HD + kk + 1) * XSS + b] = cv.f[1];
      }
    }
    __syncthreads();

    // --- GEMM: gates[8b x 80c] = x^T * Wslice ---
    float acc[4][4] = {{0.f,0.f,0.f,0.f},{0.f,0.f,0.f,0.f},
                       {0.f,0.f,0.f,0.f},{0.f,0.f,0.f,0.f}};
#pragma unroll
    for (int j = 0; j < 40; ++j) {
      int k = j * 8 + kg;
      float4 xv = *(const float4*)(xs + k * XSS + bq * 4);
      float4 wv = wr[j];
      float xx[4] = {xv.x, xv.y, xv.z, xv.w};
      float ww[4] = {wv.x, wv.y, wv.z, wv.w};
#pragma unroll
      for (int ci = 0; ci < 4; ++ci)
#pragma unroll
        for (int bi = 0; bi < 4; ++bi)
          acc[ci][bi] = __builtin_fmaf(ww[ci], xx[bi], acc[ci][bi]);
    }
#pragma unroll
    for (int mm = 1; mm < 8; mm <<= 1)
#pragma unroll
      for (int ci = 0; ci < 4; ++ci)
#pragma unroll
        for (int bi = 0; bi < 4; ++bi)
          acc[ci][bi] += __shfl_xor(acc[ci][bi], mm, 64);
    if (kg == 0) {
#pragma unroll
      for (int ci = 0; ci < 4; ++ci)
#pragma unroll
        for (int bi = 0; bi < 4; ++bi)
          gates[(bq * 4 + bi) * COLS + cq * 4 + ci] = acc[ci][bi];
    }
    __syncthreads();

    // --- cell (tid<128) || next-step stack indices (tid 256..263) ---
    if (tid < QB * DIMS) {
      const int b = tid >> 4, dl = tid & 15;
      const int gb = bg * QB + b;
      const int d = ct * DIMS + dl;
      float gi  = gates[b * COLS + dl]      + bsl[dl];
      float gfl = gates[b * COLS + 16 + dl] + bsl[16 + dl];
      float gfr = gates[b * COLS + 32 + dl] + bsl[32 + dl];
      float go  = gates[b * COLS + 48 + dl] + bsl[48 + dl];
      float gu  = gates[b * COLS + 64 + dl] + bsl[64 + dl];
      float cl, cr;
      if (maskA[pb][b]) {
        cl = gload32(c_st + ((size_t)lidxA[pb][b] * NBAT + gb) * HD + d);
        cr = gload32(c_st + ((size_t)ridxA[pb][b] * NBAT + gb) * HD + d);
      } else {
        cl = lsh[d]; cr = lsh[d];
      }
      float cc = sigf(gi) * tanh_(gu) + sigf(gfl) * cl + sigf(gfr) * cr;
      float hh = sigf(go) * tanh_(cc);
      size_t so = ((size_t)t * NBAT + gb) * HD + d;
      gstore32(h_st + so, hh);
      gstore32(c_st + so, cc);
      if (t == D - 1) {
        out[(size_t)gb * HD + d] = cc;
        out[(size_t)NBAT * HD + (size_t)gb * HD + d] = hh;
      }
    } else if (tid >= 256 && tid < 256 + QB) {
      int tn = t + 1;
      if (tn < D) {
        int b = tid - 256, gb = bg * QB + b;
        int m = trans[tn * NBAT + gb];
        int p = pptr[b];
        int li = 0, ri = 0;
        if (m) { ri = stk[b][p - 1]; li = stk[b][p - 2]; }
        int np = p - 2 * m;
        stk[b][np] = (unsigned short)tn;
        pptr[b] = np + 1;
        lidxA[tn & 1][b] = li; ridxA[tn & 1][b] = ri; maskA[tn & 1][b] = m;
      }
    }
    __syncthreads();   // drains each wave's sc1 stores (vmcnt 0 before barrier)
    if (tid == 0) {
      uint8_t* fp = flg + ((size_t)t * 32 + bg) * FLGS + ct;
      __hip_atomic_store(fp, (uint8_t)1, __ATOMIC_RELEASE, __HIP_MEMORY_SCOPE_AGENT);
    }
  }
}

extern "C" void kernel_launch(void* const* d_in, const int* in_sizes, int n_in,
                              void* d_out, int out_size, void* d_ws, size_t ws_size,
                              hipStream_t stream) {
  (void)in_sizes; (void)n_in; (void)out_size; (void)ws_size;
  const int*   trans  = (const int*)d_in[0];
  const int*   labels = (const int*)d_in[1];
  const float* emb    = (const float*)d_in[2];
  const float* W      = (const float*)d_in[3];
  const float* bias   = (const float*)d_in[4];
  const float* leaf   = (const float*)d_in[5];
  float* out = (float*)d_out;

  // ws: [0,1MB) flags (512*32*64B) | h_st 64MB | c_st 64MB
  uint8_t* ws = (uint8_t*)d_ws;
  uint8_t* flg = ws;
  float* h_st = (float*)(ws + (1 << 20));
  float* c_st = h_st + (size_t)D * NBAT * HD;

  const int flag_words = D * 32 * FLGS / 4;  // 524288... (1MB/4)
  zero_kernel<<<dim3((flag_words + 255) / 256), dim3(256), 0, stream>>>(
      (unsigned*)flg, flag_words);
  spinn_kernel<<<dim3(256), dim3(NTHR), 0, stream>>>(
      trans, labels, emb, W, bias, leaf, out, flg, h_st, c_st);
}

// Round 3
// 3546.416 us; speedup vs baseline: 3.0943x; 1.1850x over previous
//
#include <hip/hip_runtime.h>
#include <stdint.h>

// SPINN thin-stack TreeLSTM, MI355X persistent-group design, round 3.
// 32 groups x 8 blocks; block owns 16 H-dims (80 gate cols), W in regs.
// R3 vs R2:
//  - flag store RELAXED (release emitted wbl2/extra drain each step)
//  - (mask, li) precomputed for all steps at init; ri==t-1 always on reduce
//  - critical path reduced to hr=h[t-1] only (contiguous 4KB row);
//    cr = own block's prev-step output (LDS); cl/hl (<=t-2) + emb prefetched
//    one step ahead into double-buffered xs during GEMM/cell
//  - all xs scatter writes remapped with b in low 3 lane bits: bank stride
//    (24j+b) -> exact 2-way aliasing = free (was 16-way, 1.4k cyc/step)

#define D     512
#define NBAT  256
#define HD    128
#define LD    64
#define KDIM  320   // L + 2H
#define COLS  80    // 5 gates * 16 dims
#define QB    8
#define DIMS  16
#define NTHR  320
#define XSS   12    // xs row stride
#define FLGS  64    // bytes per (t,group) flag line

typedef unsigned long long u64t;

__device__ __forceinline__ float sigf(float x){ return 1.0f/(1.0f+__expf(-x)); }
__device__ __forceinline__ float tanh_(float x){ return 1.0f-2.0f/(__expf(2.0f*x)+1.0f); }
__device__ __forceinline__ u64t gload64(const float* p){
  return __hip_atomic_load((const u64t*)p, __ATOMIC_RELAXED, __HIP_MEMORY_SCOPE_AGENT);
}
__device__ __forceinline__ void gstore32(float* p, float v){
  __hip_atomic_store(p, v, __ATOMIC_RELAXED, __HIP_MEMORY_SCOPE_AGENT);
}

__global__ void zero_kernel(unsigned* p, int n){
  int i = blockIdx.x*blockDim.x + threadIdx.x;
  if (i < n) p[i] = 0u;
}

__global__ __launch_bounds__(NTHR,1) void spinn_kernel(
    const int* __restrict__ trans, const int* __restrict__ labels,
    const float* __restrict__ emb, const float* __restrict__ W,
    const float* __restrict__ bias, const float* __restrict__ leaf,
    float* __restrict__ out, uint8_t* __restrict__ flg,
    float* __restrict__ h_st, float* __restrict__ c_st)
{
  const int bid = blockIdx.x, bg = bid>>3, ct = bid&7, tid = threadIdx.x;

  __shared__ __align__(16) float xs[2][KDIM*XSS];   // 30720 B
  __shared__ float gates[QB*COLS];
  __shared__ float bsl[COLS];
  __shared__ float lsh[HD];
  __shared__ float clbuf[2][QB][DIMS];   // prefetched c[li] for own dims
  __shared__ float cloc[2][QB][DIMS];    // own c output of prev step
  __shared__ uint8_t maskS[D][QB];
  __shared__ unsigned short liS[D][QB];
  __shared__ unsigned short stk[QB][D];

  const int kg = tid&7, bq = (tid>>3)&1, cq = tid>>4;
  const int gcol = (cq>>2)*HD + ct*DIMS + (cq&3)*4;

  // weight slice into registers (once)
  float4 wr[40];
#pragma unroll
  for (int j=0;j<40;++j){ int k=j*8+kg; wr[j]=*(const float4*)(W+(size_t)k*640+gcol); }
  if (tid < COLS){ int g=tid>>4, dl=tid&15; bsl[tid]=bias[g*HD+ct*DIMS+dl]; }
  if (tid < HD) lsh[tid]=leaf[tid];
  // precompute per-step (mask, li); ri == t-1 always when mask==1
  if (tid < QB){
    int b=tid, gb=bg*QB+b, p=0;
    for (int t=0;t<D;++t){
      int m = trans[t*NBAT+gb];
      int li = 0;
      if (m) li = stk[b][p-2];
      maskS[t][b]=(uint8_t)m; liS[t][b]=(unsigned short)li;
      int np = p - 2*m; stk[b][np]=(unsigned short)t; p = np+1;
    }
  }
  __syncthreads();

  // prefill xs[0] (mask==0 at t=0 for all b by schedule construction)
  if (tid < 256){
    int b=tid&7, j=(tid>>3)&7, ii=tid>>6;
    int kk=(j+8*ii)*2, kkB=(j+8*(ii+4))*2;
    int row = labels[bg*QB+b];
    float2 e = *(const float2*)(emb + (size_t)row*LD + kk);
    xs[0][kk*XSS+b]=e.x; xs[0][(kk+1)*XSS+b]=e.y;
    xs[0][(LD+kk)*XSS+b]=lsh[kk];        xs[0][(LD+kk+1)*XSS+b]=lsh[kk+1];
    xs[0][(LD+kkB)*XSS+b]=lsh[kkB];      xs[0][(LD+kkB+1)*XSS+b]=lsh[kkB+1];
    xs[0][(LD+HD+kk)*XSS+b]=lsh[kk];     xs[0][(LD+HD+kk+1)*XSS+b]=lsh[kk+1];
    xs[0][(LD+HD+kkB)*XSS+b]=lsh[kkB];   xs[0][(LD+HD+kkB+1)*XSS+b]=lsh[kkB+1];
  }
  __syncthreads();

  const u64t GOAL = 0x0101010101010101ULL;

  for (int t=0;t<D;++t){
    const int cur = t&1, nxt = cur^1, t2 = t+1;
    const int b8 = tid&7, j8 = (tid>>3)&7, i8 = tid>>6;   // chunk coords (tid<256)
    const int kkA = (j8+8*i8)*2, kkB = (j8+8*(i8+4))*2;

    // --- A: emb prefetch (no dependency) || poll flag[t-1] ---
    float2 embv = {0.f,0.f};
    if (tid < 256 && t2 < D){
      int row = labels[t2*NBAT + bg*QB + b8];
      embv = *(const float2*)(emb + (size_t)row*LD + kkA);
    }
    if (tid == 319 && t > 0){
      const u64t* fp = (const u64t*)(flg + ((size_t)(t-1)*32 + bg)*FLGS);
      int it = 0;
      while (__hip_atomic_load(fp, __ATOMIC_RELAXED, __HIP_MEMORY_SCOPE_AGENT) != GOAL){
        __builtin_amdgcn_s_sleep(1);
        if (++it > (1<<22)) break;   // safety: hang -> wrong answer
      }
    }
    __syncthreads();

    // --- C: hr loads (critical) + hl/cl prefetch loads for t+1 ---
    u64t hrv0=0, hrv1=0, hlv0=0, hlv1=0, clv=0;
    if (t > 0 && tid < 256 && maskS[t][b8]){
      const float* hrow = h_st + ((size_t)(t-1)*NBAT + bg*QB + b8)*HD;
      hrv0 = gload64(hrow + kkA);
      hrv1 = gload64(hrow + kkB);
    }
    if (t2 < D){
      if (tid < 256){
        if (maskS[t2][b8]){
          const float* hlrow = h_st + ((size_t)liS[t2][b8]*NBAT + bg*QB + b8)*HD;
          hlv0 = gload64(hlrow + kkA);
          hlv1 = gload64(hlrow + kkB);
        }
      } else {
        int b = (tid-256)>>3, j = (tid-256)&7;
        if (maskS[t2][b])
          clv = gload64(c_st + ((size_t)liS[t2][b]*NBAT + bg*QB + b)*HD + ct*DIMS + j*2);
      }
    }
    // write hr into xs[cur]
    if (t > 0 && tid < 256 && maskS[t][b8]){
      union { u64t u; float f[2]; } u0, u1; u0.u = hrv0; u1.u = hrv1;
      xs[cur][(LD+HD+kkA)*XSS+b8]=u0.f[0]; xs[cur][(LD+HD+kkA+1)*XSS+b8]=u0.f[1];
      xs[cur][(LD+HD+kkB)*XSS+b8]=u1.f[0]; xs[cur][(LD+HD+kkB+1)*XSS+b8]=u1.f[1];
    }
    __syncthreads();

    // --- E: GEMM gates[8b x 80c] = x^T * Wslice ---
    float acc[4][4] = {{0.f,0.f,0.f,0.f},{0.f,0.f,0.f,0.f},
                       {0.f,0.f,0.f,0.f},{0.f,0.f,0.f,0.f}};
#pragma unroll
    for (int j=0;j<40;++j){
      int k = j*8 + kg;
      float4 xv = *(const float4*)(xs[cur] + k*XSS + bq*4);
      float4 wv = wr[j];
      float xx[4]={xv.x,xv.y,xv.z,xv.w};
      float ww[4]={wv.x,wv.y,wv.z,wv.w};
#pragma unroll
      for (int ci=0;ci<4;++ci)
#pragma unroll
        for (int bi=0;bi<4;++bi)
          acc[ci][bi] = __builtin_fmaf(ww[ci], xx[bi], acc[ci][bi]);
    }
#pragma unroll
    for (int mm=1;mm<8;mm<<=1)
#pragma unroll
      for (int ci=0;ci<4;++ci)
#pragma unroll
        for (int bi=0;bi<4;++bi)
          acc[ci][bi] += __shfl_xor(acc[ci][bi], mm, 64);
    if (kg == 0){
#pragma unroll
      for (int ci=0;ci<4;++ci)
#pragma unroll
        for (int bi=0;bi<4;++bi)
          gates[(bq*4+bi)*COLS + cq*4 + ci] = acc[ci][bi];
    }
    __syncthreads();

    // --- F: cell (tid<128) + prefetch writes into xs[nxt]/clbuf[nxt] ---
    if (tid < QB*DIMS){
      const int b = tid>>4, dl = tid&15, gb = bg*QB+b, d = ct*DIMS+dl;
      const int m = maskS[t][b];
      float gi  = gates[b*COLS + dl]      + bsl[dl];
      float gfl = gates[b*COLS + 16+dl]   + bsl[16+dl];
      float gfr = gates[b*COLS + 32+dl]   + bsl[32+dl];
      float go  = gates[b*COLS + 48+dl]   + bsl[48+dl];
      float gu  = gates[b*COLS + 64+dl]   + bsl[64+dl];
      float cl_ = m ? clbuf[cur][b][dl] : lsh[d];
      float cr_ = m ? cloc[nxt][b][dl]  : lsh[d];   // cloc[(t-1)&1] = own c[t-1]
      float cc = sigf(gi)*tanh_(gu) + sigf(gfl)*cl_ + sigf(gfr)*cr_;
      float hh = sigf(go)*tanh_(cc);
      size_t so = ((size_t)t*NBAT + gb)*HD + d;
      gstore32(h_st + so, hh);
      gstore32(c_st + so, cc);
      cloc[cur][b][dl] = cc;
      if (t == D-1){
        out[(size_t)gb*HD + d] = cc;
        out[(size_t)NBAT*HD + (size_t)gb*HD + d] = hh;
      }
    }
    if (t2 < D){
      if (tid < 256){
        xs[nxt][kkA*XSS+b8]=embv.x; xs[nxt][(kkA+1)*XSS+b8]=embv.y;
        if (maskS[t2][b8]){
          union { u64t u; float f[2]; } u0, u1; u0.u = hlv0; u1.u = hlv1;
          xs[nxt][(LD+kkA)*XSS+b8]=u0.f[0]; xs[nxt][(LD+kkA+1)*XSS+b8]=u0.f[1];
          xs[nxt][(LD+kkB)*XSS+b8]=u1.f[0]; xs[nxt][(LD+kkB+1)*XSS+b8]=u1.f[1];
        } else {
          xs[nxt][(LD+kkA)*XSS+b8]=lsh[kkA];      xs[nxt][(LD+kkA+1)*XSS+b8]=lsh[kkA+1];
          xs[nxt][(LD+kkB)*XSS+b8]=lsh[kkB];      xs[nxt][(LD+kkB+1)*XSS+b8]=lsh[kkB+1];
          xs[nxt][(LD+HD+kkA)*XSS+b8]=lsh[kkA];   xs[nxt][(LD+HD+kkA+1)*XSS+b8]=lsh[kkA+1];
          xs[nxt][(LD+HD+kkB)*XSS+b8]=lsh[kkB];   xs[nxt][(LD+HD+kkB+1)*XSS+b8]=lsh[kkB+1];
        }
      } else {
        int b = (tid-256)>>3, j = (tid-256)&7;
        if (maskS[t2][b]){
          union { u64t u; float f[2]; } u0; u0.u = clv;
          clbuf[nxt][b][j*2]   = u0.f[0];
          clbuf[nxt][b][j*2+1] = u0.f[1];
        }
      }
    }
    __syncthreads();   // per-wave s_waitcnt vmcnt(0) -> h/c stores at LLC
    if (tid == 0){
      uint8_t* fp = flg + ((size_t)t*32 + bg)*FLGS + ct;
      __hip_atomic_store(fp, (uint8_t)1, __ATOMIC_RELAXED, __HIP_MEMORY_SCOPE_AGENT);
    }
  }
}

extern "C" void kernel_launch(void* const* d_in, const int* in_sizes, int n_in,
                              void* d_out, int out_size, void* d_ws, size_t ws_size,
                              hipStream_t stream) {
  (void)in_sizes; (void)n_in; (void)out_size; (void)ws_size;
  const int*   trans  = (const int*)d_in[0];
  const int*   labels = (const int*)d_in[1];
  const float* emb    = (const float*)d_in[2];
  const float* W      = (const float*)d_in[3];
  const float* bias   = (const float*)d_in[4];
  const float* leaf   = (const float*)d_in[5];
  float* out = (float*)d_out;

  // ws: [0,1MB) flags | h_st 64MB | c_st 64MB
  uint8_t* ws = (uint8_t*)d_ws;
  uint8_t* flgp = ws;
  float* h_st = (float*)(ws + (1<<20));
  float* c_st = h_st + (size_t)D*NBAT*HD;

  const int flag_words = D*32*FLGS/4;
  zero_kernel<<<dim3((flag_words+255)/256), dim3(256), 0, stream>>>((unsigned*)flgp, flag_words);
  spinn_kernel<<<dim3(256), dim3(NTHR), 0, stream>>>(
      trans, labels, emb, W, bias, leaf, out, flgp, h_st, c_st);
}